// Round 4
// baseline (351.891 us; speedup 1.0000x reference)
//
#include <hip/hip_runtime.h>

#define TT 16384
#define DD 4096
#define OO 4096
#define NE 8
#define RRK 64
#define KSPLIT 8
#define KCHUNK 512

typedef _Float16 f16x8 __attribute__((ext_vector_type(8)));
typedef _Float16 f16x4 __attribute__((ext_vector_type(4)));
typedef float f32x4 __attribute__((ext_vector_type(4)));

// workspace layout (bytes)
#define CNT_OFF 0             // 8 ints
#define PERM_OFF 1024         // 8*TT ints = 512KB
#define AT_OFF (1u << 20)     // 8*64*4096 f16 = 4MB: A^T [e][r][k]
#define BT_OFF (5u << 20)     // 8*4096*64 f16 = 4MB: B^T [e][o][r]
#define HP_OFF (9u << 20)     // 8*TT*64 f32 = 32MB: H k-partials, unscaled
#define H_OFF (41u << 20)     // TT*64 f16 = 2MB: reduced+scaled H

// ---------------------------------------------------------------------------
// prep: scatter tokens into per-adapter buckets; transpose+cast A and B to f16
// ---------------------------------------------------------------------------
__global__ void prep_kernel(const int* __restrict__ ids,
                            const float* __restrict__ A,
                            const float* __restrict__ B,
                            int* __restrict__ cnt,
                            int* __restrict__ perm,
                            _Float16* __restrict__ At,
                            _Float16* __restrict__ Bt) {
  const int bid = blockIdx.x, tid = threadIdx.x;
  if (bid < 64) {                      // scatter
    int t = bid * 256 + tid;
    int e = ids[t];
    int pos = atomicAdd(&cnt[e], 1);
    perm[e * TT + pos] = t;
    return;
  }
  __shared__ float tile[64][65];
  if (bid < 576) {                     // A[e][k][r] -> At[e][r][k]
    int idx = bid - 64;
    int e = idx >> 6, kb = (idx & 63) << 6;
    #pragma unroll
    for (int i = 0; i < 16; ++i) {
      int lin = i * 256 + tid;
      int kr = lin >> 6, r = lin & 63;
      tile[kr][r] = A[((size_t)e * DD + kb + kr) * RRK + r];
    }
    __syncthreads();
    #pragma unroll
    for (int i = 0; i < 16; ++i) {
      int lin = i * 256 + tid;
      int r = lin >> 6, kk = lin & 63;
      At[((size_t)e * RRK + r) * DD + kb + kk] = (_Float16)tile[kk][r];
    }
  } else {                             // B[e][r][o] -> Bt[e][o][r]
    int idx = bid - 576;
    int e = idx >> 6, ob = (idx & 63) << 6;
    #pragma unroll
    for (int i = 0; i < 16; ++i) {
      int lin = i * 256 + tid;
      int r = lin >> 6, o = lin & 63;
      tile[r][o] = B[((size_t)e * RRK + r) * OO + ob + o];
    }
    __syncthreads();
    #pragma unroll
    for (int i = 0; i < 16; ++i) {
      int lin = i * 256 + tid;
      int o = lin >> 6, r2 = lin & 63;
      Bt[((size_t)e * OO + ob + o) * RRK + r2] = (_Float16)tile[r2][o];
    }
  }
}

// ---------------------------------------------------------------------------
// stage 1: HP[s][t][:] = x[t][ks..] @ A[e][ks..]   (k-split 8, f32, unscaled)
// 2 M-tiles per block share the At fragments; 8 x-float4 issued per k-step.
// Barrier-free, LDS-free.
// ---------------------------------------------------------------------------
__global__ __launch_bounds__(256, 3)
void lora_stage1(const float* __restrict__ x,
                 const _Float16* __restrict__ At,
                 const int* __restrict__ cnt,
                 const int* __restrict__ perm,
                 float* __restrict__ HP) {
  const int tid = threadIdx.x;
  const int lane = tid & 63, w = tid >> 6;
  const int lr = lane & 15;
  const int kq = (lane >> 4) << 3;

  int tot = 0;
  #pragma unroll
  for (int ee = 0; ee < NE; ++ee) {
    int tl = (cnt[ee] + 63) >> 6;
    tot += ((tl + 1) >> 1) * KSPLIT;
  }

  for (int wi = blockIdx.x; wi < tot; wi += gridDim.x) {
    int e = 0, base = 0, n_e = 0;
    {
      int acc0 = 0;
      #pragma unroll
      for (int ee = 0; ee < NE; ++ee) {
        int c = cnt[ee];
        int work = ((((c + 63) >> 6) + 1) >> 1) * KSPLIT;
        if (wi >= acc0 && wi < acc0 + work) { e = ee; base = acc0; n_e = c; }
        acc0 += work;
      }
    }
    int local = wi - base;
    int s = local & (KSPLIT - 1);
    int ch = local >> 3;
    int kbase = s * KCHUNK;
    int m0 = ch << 7;                 // 2 tiles of 64 tokens

    const int prow = e * TT;
    int arow0 = m0 + w * 16 + lr;
    int arow1 = arow0 + 64;
    int atok0 = perm[prow + (arow0 < n_e ? arow0 : n_e - 1)];
    int atok1 = perm[prow + (arow1 < n_e ? arow1 : n_e - 1)];
    const float* xp0 = x + (size_t)atok0 * DD + kbase + kq;
    const float* xp1 = x + (size_t)atok1 * DD + kbase + kq;
    const _Float16* ap = At + (size_t)e * RRK * DD + kbase + kq;

    f32x4 acc0[4] = {};
    f32x4 acc1[4] = {};

    for (int k0 = 0; k0 < KCHUNK; k0 += 64) {
      // batched x loads: 8 independent float4 (HBM stream)
      float4 u00 = *(const float4*)(xp0 + k0);
      float4 u01 = *(const float4*)(xp0 + k0 + 4);
      float4 u02 = *(const float4*)(xp0 + k0 + 32);
      float4 u03 = *(const float4*)(xp0 + k0 + 36);
      float4 u10 = *(const float4*)(xp1 + k0);
      float4 u11 = *(const float4*)(xp1 + k0 + 4);
      float4 u12 = *(const float4*)(xp1 + k0 + 32);
      float4 u13 = *(const float4*)(xp1 + k0 + 36);
      // At fragments (L2), shared by both tiles
      f16x8 at[4][2];
      #pragma unroll
      for (int nf = 0; nf < 4; ++nf) {
        #pragma unroll
        for (int ks = 0; ks < 2; ++ks)
          at[nf][ks] = *(const f16x8*)(ap + (size_t)(nf * 16 + lr) * DD + k0 + ks * 32);
      }
      f16x8 xa0[2], xa1[2];
      xa0[0][0]=(_Float16)u00.x; xa0[0][1]=(_Float16)u00.y; xa0[0][2]=(_Float16)u00.z; xa0[0][3]=(_Float16)u00.w;
      xa0[0][4]=(_Float16)u01.x; xa0[0][5]=(_Float16)u01.y; xa0[0][6]=(_Float16)u01.z; xa0[0][7]=(_Float16)u01.w;
      xa0[1][0]=(_Float16)u02.x; xa0[1][1]=(_Float16)u02.y; xa0[1][2]=(_Float16)u02.z; xa0[1][3]=(_Float16)u02.w;
      xa0[1][4]=(_Float16)u03.x; xa0[1][5]=(_Float16)u03.y; xa0[1][6]=(_Float16)u03.z; xa0[1][7]=(_Float16)u03.w;
      xa1[0][0]=(_Float16)u10.x; xa1[0][1]=(_Float16)u10.y; xa1[0][2]=(_Float16)u10.z; xa1[0][3]=(_Float16)u10.w;
      xa1[0][4]=(_Float16)u11.x; xa1[0][5]=(_Float16)u11.y; xa1[0][6]=(_Float16)u11.z; xa1[0][7]=(_Float16)u11.w;
      xa1[1][0]=(_Float16)u12.x; xa1[1][1]=(_Float16)u12.y; xa1[1][2]=(_Float16)u12.z; xa1[1][3]=(_Float16)u12.w;
      xa1[1][4]=(_Float16)u13.x; xa1[1][5]=(_Float16)u13.y; xa1[1][6]=(_Float16)u13.z; xa1[1][7]=(_Float16)u13.w;
      #pragma unroll
      for (int ks = 0; ks < 2; ++ks) {
        #pragma unroll
        for (int nf = 0; nf < 4; ++nf) {
          acc0[nf] = __builtin_amdgcn_mfma_f32_16x16x32_f16(xa0[ks], at[nf][ks], acc0[nf], 0, 0, 0);
          acc1[nf] = __builtin_amdgcn_mfma_f32_16x16x32_f16(xa1[ks], at[nf][ks], acc1[nf], 0, 0, 0);
        }
      }
    }

    const int rq = (lane >> 4) << 2;
    #pragma unroll
    for (int rg = 0; rg < 4; ++rg) {
      int row0 = m0 + w * 16 + rq + rg;
      if (row0 < n_e) {
        int tk = perm[prow + row0];
        float* hp = HP + ((size_t)s * TT + tk) * RRK + lr;
        #pragma unroll
        for (int nf = 0; nf < 4; ++nf) hp[nf * 16] = acc0[nf][rg];
      }
      int row1 = row0 + 64;
      if (row1 < n_e) {
        int tk = perm[prow + row1];
        float* hp = HP + ((size_t)s * TT + tk) * RRK + lr;
        #pragma unroll
        for (int nf = 0; nf < 4; ++nf) hp[nf * 16] = acc1[nf][rg];
      }
    }
  }
}

// ---------------------------------------------------------------------------
// reduce: H[t][r] = scaling[ids[t]] * sum_s HP[s][t][r]   (f32 -> f16)
// ---------------------------------------------------------------------------
__global__ void lora_reduce(const float* __restrict__ HP,
                            const float* __restrict__ scaling,
                            const int* __restrict__ ids,
                            _Float16* __restrict__ H) {
  int i = blockIdx.x * 256 + threadIdx.x;
  int t = i >> 4;
  int rg = (i & 15) << 2;
  float s = scaling[ids[t]];
  f32x4 sum = {};
  #pragma unroll
  for (int sp = 0; sp < KSPLIT; ++sp) {
    sum += *(const f32x4*)(HP + ((size_t)sp * TT + t) * RRK + rg);
  }
  f16x4 h;
  #pragma unroll
  for (int j = 0; j < 4; ++j) h[j] = (_Float16)(sum[j] * s);
  *(f16x4*)(H + (size_t)t * RRK + rg) = h;
}

// ---------------------------------------------------------------------------
// stage 2: out[t][:] = base[t][:] + H[t] @ B[e]
// Block owns (adapter, 128-col o-panel, chunk of 4 M-tiles). B fragments
// hoisted to registers once; M-loop barrier-free with H prefetch.
// D = B^T(A-op) x H^T(B-op): lane owns one token row, float4 epilogue.
// ---------------------------------------------------------------------------
__global__ __launch_bounds__(256, 3)
void lora_stage2(const float* __restrict__ baseo,
                 const _Float16* __restrict__ Bt,
                 const _Float16* __restrict__ H,
                 const int* __restrict__ cnt,
                 const int* __restrict__ perm,
                 float* __restrict__ out) {
  const int tid = threadIdx.x;
  const int lane = tid & 63, w = tid >> 6;
  const int lr = lane & 15;
  const int kq = (lane >> 4) << 3;
  const int g4 = (lane >> 4) << 2;

  int tot = 0;
  #pragma unroll
  for (int ee = 0; ee < NE; ++ee) {
    int tl = (cnt[ee] + 63) >> 6;
    tot += ((tl + 3) >> 2) << 5;       // chunks of 4 tiles x 32 panels
  }

  for (int wi = blockIdx.x; wi < tot; wi += gridDim.x) {
    int e = 0, base = 0, n_e = 0;
    {
      int acc0 = 0;
      #pragma unroll
      for (int ee = 0; ee < NE; ++ee) {
        int c = cnt[ee];
        int work = ((((c + 63) >> 6) + 3) >> 2) << 5;
        if (wi >= acc0 && wi < acc0 + work) { e = ee; base = acc0; n_e = c; }
        acc0 += work;
      }
    }
    int local = wi - base;
    int panel = local & 31;            // consecutive blocks share H tiles
    int ch = local >> 5;
    int o0 = panel << 7;
    int tbase = ch << 2;
    int tiles_m = (n_e + 63) >> 6;
    int ntile = tiles_m - tbase;
    if (ntile > 4) ntile = 4;

    // hoist B fragments: 8 o-frags x 2 k-slices = 64 VGPR, loaded once
    f16x8 bf0[8], bf1[8];
    {
      const _Float16* bp = Bt + ((size_t)e * OO + o0 + lr) * RRK + kq;
      #pragma unroll
      for (int of = 0; of < 8; ++of) {
        bf0[of] = *(const f16x8*)(bp + (size_t)of * 16 * RRK);
        bf1[of] = *(const f16x8*)(bp + (size_t)of * 16 * RRK + 32);
      }
    }

    const int prow = e * TT;
    int row_c = tbase * 64 + w * 16 + lr;
    bool v_c = row_c < n_e;
    int tk_c = perm[prow + (v_c ? row_c : n_e - 1)];
    f16x8 hf0_c = *(const f16x8*)(H + (size_t)tk_c * RRK + kq);
    f16x8 hf1_c = *(const f16x8*)(H + (size_t)tk_c * RRK + kq + 32);

    for (int m = 0; m < ntile; ++m) {
      // prefetch next tile's perm + H while computing current
      int row_n = row_c + 64;
      bool v_n = false; int tk_n = tk_c;
      f16x8 hf0_n = hf0_c, hf1_n = hf1_c;
      if (m + 1 < ntile) {
        v_n = row_n < n_e;
        tk_n = perm[prow + (v_n ? row_n : n_e - 1)];
        hf0_n = *(const f16x8*)(H + (size_t)tk_n * RRK + kq);
        hf1_n = *(const f16x8*)(H + (size_t)tk_n * RRK + kq + 32);
      }

      f32x4 acc[8];
      #pragma unroll
      for (int of = 0; of < 8; ++of) acc[of] = (f32x4){0.f, 0.f, 0.f, 0.f};
      #pragma unroll
      for (int of = 0; of < 8; ++of) {
        acc[of] = __builtin_amdgcn_mfma_f32_16x16x32_f16(bf0[of], hf0_c, acc[of], 0, 0, 0);
        acc[of] = __builtin_amdgcn_mfma_f32_16x16x32_f16(bf1[of], hf1_c, acc[of], 0, 0, 0);
      }

      if (v_c) {
        size_t rowoff = (size_t)tk_c * OO + o0 + g4;
        #pragma unroll
        for (int of = 0; of < 8; ++of) {
          size_t off2 = rowoff + (size_t)of * 16;
          float4 b4 = *(const float4*)(baseo + off2);
          float4 r4;
          r4.x = b4.x + acc[of][0];
          r4.y = b4.y + acc[of][1];
          r4.z = b4.z + acc[of][2];
          r4.w = b4.w + acc[of][3];
          *(float4*)(out + off2) = r4;
        }
      }
      row_c = row_n; v_c = v_n; tk_c = tk_n; hf0_c = hf0_n; hf1_c = hf1_n;
    }
  }
}

extern "C" void kernel_launch(void* const* d_in, const int* in_sizes, int n_in,
                              void* d_out, int out_size, void* d_ws, size_t ws_size,
                              hipStream_t stream) {
  const float* x = (const float*)d_in[0];
  const float* baseo = (const float*)d_in[1];
  const float* A = (const float*)d_in[2];
  const float* B = (const float*)d_in[3];
  const float* scaling = (const float*)d_in[4];
  const int* ids = (const int*)d_in[5];
  float* out = (float*)d_out;
  char* ws = (char*)d_ws;

  int* cnt = (int*)(ws + CNT_OFF);
  int* perm = (int*)(ws + PERM_OFF);
  _Float16* At = (_Float16*)(ws + AT_OFF);
  _Float16* Bt = (_Float16*)(ws + BT_OFF);
  float* HP = (float*)(ws + HP_OFF);
  _Float16* H = (_Float16*)(ws + H_OFF);

  hipMemsetAsync(cnt, 0, NE * sizeof(int), stream);
  hipLaunchKernelGGL(prep_kernel, dim3(1088), dim3(256), 0, stream,
                     ids, A, B, cnt, perm, At, Bt);
  hipLaunchKernelGGL(lora_stage1, dim3(1088), dim3(256), 0, stream,
                     x, At, cnt, perm, HP);
  hipLaunchKernelGGL(lora_reduce, dim3(1024), dim3(256), 0, stream,
                     HP, scaling, ids, H);
  hipLaunchKernelGGL(lora_stage2, dim3(2048), dim3(256), 0, stream,
                     baseo, Bt, H, cnt, perm, out);
}

// Round 5
// 338.358 us; speedup vs baseline: 1.0400x; 1.0400x over previous
//
#include <hip/hip_runtime.h>

#define TT 16384
#define DD 4096
#define OO 4096
#define NE 8
#define RRK 64
#define KSPLIT 4
#define KCHUNK 1024

typedef _Float16 f16x8 __attribute__((ext_vector_type(8)));
typedef _Float16 f16x4 __attribute__((ext_vector_type(4)));
typedef float f32x4 __attribute__((ext_vector_type(4)));

// workspace layout (bytes)
#define CNT_OFF 0             // 8 ints
#define PERM_OFF 1024         // 8*TT ints = 512KB
#define AT_OFF (1u << 20)     // 8*64*4096 f16 = 4MB: A^T [e][r][k]
#define BT_OFF (5u << 20)     // 8*4096*64 f16 = 4MB: B^T [e][o][r]
#define HP_OFF (9u << 20)     // 4*TT*64 f16 = 8MB: H k-partials, unscaled
#define H_OFF (18u << 20)     // TT*64 f16 = 2MB: reduced+scaled H

// ---------------------------------------------------------------------------
// prep: scatter tokens into per-adapter buckets; transpose+cast A and B to f16
// ---------------------------------------------------------------------------
__global__ void prep_kernel(const int* __restrict__ ids,
                            const float* __restrict__ A,
                            const float* __restrict__ B,
                            int* __restrict__ cnt,
                            int* __restrict__ perm,
                            _Float16* __restrict__ At,
                            _Float16* __restrict__ Bt) {
  const int bid = blockIdx.x, tid = threadIdx.x;
  if (bid < 64) {                      // scatter
    int t = bid * 256 + tid;
    int e = ids[t];
    int pos = atomicAdd(&cnt[e], 1);
    perm[e * TT + pos] = t;
    return;
  }
  __shared__ float tile[64][65];
  if (bid < 576) {                     // A[e][k][r] -> At[e][r][k]
    int idx = bid - 64;
    int e = idx >> 6, kb = (idx & 63) << 6;
    #pragma unroll
    for (int i = 0; i < 16; ++i) {
      int lin = i * 256 + tid;
      int kr = lin >> 6, r = lin & 63;
      tile[kr][r] = A[((size_t)e * DD + kb + kr) * RRK + r];
    }
    __syncthreads();
    #pragma unroll
    for (int i = 0; i < 16; ++i) {
      int lin = i * 256 + tid;
      int r = lin >> 6, kk = lin & 63;
      At[((size_t)e * RRK + r) * DD + kb + kk] = (_Float16)tile[kk][r];
    }
  } else {                             // B[e][r][o] -> Bt[e][o][r]
    int idx = bid - 576;
    int e = idx >> 6, ob = (idx & 63) << 6;
    #pragma unroll
    for (int i = 0; i < 16; ++i) {
      int lin = i * 256 + tid;
      int r = lin >> 6, o = lin & 63;
      tile[r][o] = B[((size_t)e * RRK + r) * OO + ob + o];
    }
    __syncthreads();
    #pragma unroll
    for (int i = 0; i < 16; ++i) {
      int lin = i * 256 + tid;
      int o = lin >> 6, r2 = lin & 63;
      Bt[((size_t)e * OO + ob + o) * RRK + r2] = (_Float16)tile[r2][o];
    }
  }
}

// ---------------------------------------------------------------------------
// stage 1: HP[s][t][:] = x[t][ks..] @ A[e][ks..]   (k-split by 4, unscaled)
// LDS-staged (coalesced, line-mergeable global requests). 64 tok x 64 R x 1024K.
// This is the measured-fast R2 structure.
// ---------------------------------------------------------------------------
__global__ __launch_bounds__(256, 2)
void lora_stage1(const float* __restrict__ x,
                 const _Float16* __restrict__ At,
                 const int* __restrict__ cnt,
                 const int* __restrict__ perm,
                 _Float16* __restrict__ HP) {
  __shared__ _Float16 Xs[64][72];
  __shared__ _Float16 As[64][72];
  __shared__ int toks[64];
  const int tid = threadIdx.x;
  const int lane = tid & 63, w = tid >> 6;

  int tiles = 0;
  #pragma unroll
  for (int ee = 0; ee < NE; ++ee) tiles += (cnt[ee] + 63) >> 6;

  for (int wi = blockIdx.x; wi < tiles * KSPLIT; wi += gridDim.x) {
    int tile = wi >> 2, s = wi & 3;
    int e = 0, base = 0, n_e = 0;
    {
      int acc0 = 0;
      #pragma unroll
      for (int ee = 0; ee < NE; ++ee) {
        int c = cnt[ee];
        int tl = (c + 63) >> 6;
        if (tile >= acc0 && tile < acc0 + tl) { e = ee; base = acc0; n_e = c; }
        acc0 += tl;
      }
    }
    int m0 = (tile - base) << 6;
    int kbase = s * KCHUNK;

    if (tid < 64) {
      int rloc = m0 + tid;
      toks[tid] = (rloc < n_e) ? perm[e * TT + rloc] : -1;
    }
    __syncthreads();

    const int srow = tid >> 2;
    const int seg = (tid & 3) << 4;
    int tk0 = toks[srow];
    if (tk0 < 0) tk0 = toks[0];
    const float* xp = x + (size_t)tk0 * DD + seg;
    const _Float16* ap = At + ((size_t)e * RRK + srow) * DD + seg;

    f32x4 acc[4] = {};

    for (int k0 = kbase; k0 < kbase + KCHUNK; k0 += 64) {
      float4 v0 = *(const float4*)(xp + k0);
      float4 v1 = *(const float4*)(xp + k0 + 4);
      float4 v2 = *(const float4*)(xp + k0 + 8);
      float4 v3 = *(const float4*)(xp + k0 + 12);
      f16x8 xa, xb;
      xa[0] = (_Float16)v0.x; xa[1] = (_Float16)v0.y;
      xa[2] = (_Float16)v0.z; xa[3] = (_Float16)v0.w;
      xa[4] = (_Float16)v1.x; xa[5] = (_Float16)v1.y;
      xa[6] = (_Float16)v1.z; xa[7] = (_Float16)v1.w;
      xb[0] = (_Float16)v2.x; xb[1] = (_Float16)v2.y;
      xb[2] = (_Float16)v2.z; xb[3] = (_Float16)v2.w;
      xb[4] = (_Float16)v3.x; xb[5] = (_Float16)v3.y;
      xb[6] = (_Float16)v3.z; xb[7] = (_Float16)v3.w;
      *(f16x8*)&Xs[srow][seg] = xa;
      *(f16x8*)&Xs[srow][seg + 8] = xb;
      *(f16x8*)&As[srow][seg] = *(const f16x8*)(ap + k0);
      *(f16x8*)&As[srow][seg + 8] = *(const f16x8*)(ap + k0 + 8);
      __syncthreads();

      const int mr = w * 16 + (lane & 15);
      const int kq = (lane >> 4) << 3;
      #pragma unroll
      for (int ks = 0; ks < 2; ++ks) {
        f16x8 af = *(const f16x8*)&Xs[mr][ks * 32 + kq];
        #pragma unroll
        for (int nf = 0; nf < 4; ++nf) {
          f16x8 bfr = *(const f16x8*)&As[nf * 16 + (lane & 15)][ks * 32 + kq];
          acc[nf] = __builtin_amdgcn_mfma_f32_16x16x32_f16(af, bfr, acc[nf], 0, 0, 0);
        }
      }
      __syncthreads();
    }

    // partial epilogue (unscaled, f16)
    const int rq = (lane >> 4) << 2;
    #pragma unroll
    for (int rg = 0; rg < 4; ++rg) {
      int tk = toks[w * 16 + rq + rg];
      if (tk >= 0) {
        _Float16* hp = HP + ((size_t)s * TT + tk) * RRK + (lane & 15);
        #pragma unroll
        for (int nf = 0; nf < 4; ++nf) {
          hp[nf * 16] = (_Float16)acc[nf][rg];
        }
      }
    }
    __syncthreads();
  }
}

// ---------------------------------------------------------------------------
// reduce: H[t][r] = scaling[ids[t]] * sum_s HP[s][t][r]   (f16 partials -> f16)
// ---------------------------------------------------------------------------
__global__ void lora_reduce(const _Float16* __restrict__ HP,
                            const float* __restrict__ scaling,
                            const int* __restrict__ ids,
                            _Float16* __restrict__ H) {
  int i = blockIdx.x * 256 + threadIdx.x;
  int t = i >> 4;
  int rg = (i & 15) << 2;
  float s = scaling[ids[t]];
  float sum[4] = {0.f, 0.f, 0.f, 0.f};
  #pragma unroll
  for (int sp = 0; sp < KSPLIT; ++sp) {
    f16x4 h = *(const f16x4*)(HP + ((size_t)sp * TT + t) * RRK + rg);
    #pragma unroll
    for (int j = 0; j < 4; ++j) sum[j] += (float)h[j];
  }
  f16x4 hv;
  #pragma unroll
  for (int j = 0; j < 4; ++j) hv[j] = (_Float16)(sum[j] * s);
  *(f16x4*)(H + (size_t)t * RRK + rg) = hv;
}

// ---------------------------------------------------------------------------
// stage 2: out[t][:] = base[t][:] + H[t] @ B[e]
// Block owns (adapter, 256-col o-panel, chunk of 4 M-tiles): per token row the
// base/out stream is 1KB contiguous (vs 512B before) for DRAM efficiency.
// B fragments held in registers across the M-loop; barrier-free, LDS-free.
// D = B^T(A-op) x H^T(B-op): lane owns one token row, float4 epilogue.
// ---------------------------------------------------------------------------
__global__ __launch_bounds__(256, 2)
void lora_stage2(const float* __restrict__ baseo,
                 const _Float16* __restrict__ Bt,
                 const _Float16* __restrict__ H,
                 const int* __restrict__ cnt,
                 const int* __restrict__ perm,
                 float* __restrict__ out) {
  const int tid = threadIdx.x;
  const int lane = tid & 63, w = tid >> 6;
  const int lr = lane & 15;
  const int kq = (lane >> 4) << 3;
  const int g4 = (lane >> 4) << 2;

  int tot = 0;
  #pragma unroll
  for (int ee = 0; ee < NE; ++ee) {
    int tl = (cnt[ee] + 63) >> 6;
    tot += ((tl + 3) >> 2) << 4;       // chunks of 4 tiles x 16 panels of 256
  }

  for (int wi = blockIdx.x; wi < tot; wi += gridDim.x) {
    int e = 0, base = 0, n_e = 0;
    {
      int acc0 = 0;
      #pragma unroll
      for (int ee = 0; ee < NE; ++ee) {
        int c = cnt[ee];
        int work = ((((c + 63) >> 6) + 3) >> 2) << 4;
        if (wi >= acc0 && wi < acc0 + work) { e = ee; base = acc0; n_e = c; }
        acc0 += work;
      }
    }
    int local = wi - base;
    int panel = local & 15;            // consecutive blocks share H tiles
    int ch = local >> 4;
    int o0 = panel << 8;
    int tbase = ch << 2;
    int tiles_m = (n_e + 63) >> 6;
    int ntile = tiles_m - tbase;
    if (ntile > 4) ntile = 4;

    // hoist B fragments: 16 o-frags x 2 k-slices = 128 VGPR, loaded once
    f16x8 bf0[16], bf1[16];
    {
      const _Float16* bp = Bt + ((size_t)e * OO + o0 + lr) * RRK + kq;
      #pragma unroll
      for (int of = 0; of < 16; ++of) {
        bf0[of] = *(const f16x8*)(bp + (size_t)of * 16 * RRK);
        bf1[of] = *(const f16x8*)(bp + (size_t)of * 16 * RRK + 32);
      }
    }

    const int prow = e * TT;
    int row_c = tbase * 64 + w * 16 + lr;
    bool v_c = row_c < n_e;
    int tk_c = perm[prow + (v_c ? row_c : n_e - 1)];
    f16x8 hf0_c = *(const f16x8*)(H + (size_t)tk_c * RRK + kq);
    f16x8 hf1_c = *(const f16x8*)(H + (size_t)tk_c * RRK + kq + 32);

    for (int m = 0; m < ntile; ++m) {
      // prefetch next tile's perm + H while computing current
      int row_n = row_c + 64;
      bool v_n = false; int tk_n = tk_c;
      f16x8 hf0_n = hf0_c, hf1_n = hf1_c;
      if (m + 1 < ntile) {
        v_n = row_n < n_e;
        tk_n = perm[prow + (v_n ? row_n : n_e - 1)];
        hf0_n = *(const f16x8*)(H + (size_t)tk_n * RRK + kq);
        hf1_n = *(const f16x8*)(H + (size_t)tk_n * RRK + kq + 32);
      }

      f32x4 acc[16];
      #pragma unroll
      for (int of = 0; of < 16; ++of) acc[of] = (f32x4){0.f, 0.f, 0.f, 0.f};
      #pragma unroll
      for (int of = 0; of < 16; ++of) {
        acc[of] = __builtin_amdgcn_mfma_f32_16x16x32_f16(bf0[of], hf0_c, acc[of], 0, 0, 0);
        acc[of] = __builtin_amdgcn_mfma_f32_16x16x32_f16(bf1[of], hf1_c, acc[of], 0, 0, 0);
      }

      if (v_c) {
        size_t rowoff = (size_t)tk_c * OO + o0 + g4;
        #pragma unroll
        for (int of = 0; of < 16; ++of) {
          size_t off2 = rowoff + (size_t)of * 16;
          float4 b4 = *(const float4*)(baseo + off2);
          float4 r4;
          r4.x = b4.x + acc[of][0];
          r4.y = b4.y + acc[of][1];
          r4.z = b4.z + acc[of][2];
          r4.w = b4.w + acc[of][3];
          *(float4*)(out + off2) = r4;
        }
      }
      row_c = row_n; v_c = v_n; tk_c = tk_n; hf0_c = hf0_n; hf1_c = hf1_n;
    }
  }
}

extern "C" void kernel_launch(void* const* d_in, const int* in_sizes, int n_in,
                              void* d_out, int out_size, void* d_ws, size_t ws_size,
                              hipStream_t stream) {
  const float* x = (const float*)d_in[0];
  const float* baseo = (const float*)d_in[1];
  const float* A = (const float*)d_in[2];
  const float* B = (const float*)d_in[3];
  const float* scaling = (const float*)d_in[4];
  const int* ids = (const int*)d_in[5];
  float* out = (float*)d_out;
  char* ws = (char*)d_ws;

  int* cnt = (int*)(ws + CNT_OFF);
  int* perm = (int*)(ws + PERM_OFF);
  _Float16* At = (_Float16*)(ws + AT_OFF);
  _Float16* Bt = (_Float16*)(ws + BT_OFF);
  _Float16* HP = (_Float16*)(ws + HP_OFF);
  _Float16* H = (_Float16*)(ws + H_OFF);

  hipMemsetAsync(cnt, 0, NE * sizeof(int), stream);
  hipLaunchKernelGGL(prep_kernel, dim3(1088), dim3(256), 0, stream,
                     ids, A, B, cnt, perm, At, Bt);
  hipLaunchKernelGGL(lora_stage1, dim3(1056), dim3(256), 0, stream,
                     x, At, cnt, perm, HP);
  hipLaunchKernelGGL(lora_reduce, dim3(1024), dim3(256), 0, stream,
                     HP, scaling, ids, H);
  hipLaunchKernelGGL(lora_stage2, dim3(1024), dim3(256), 0, stream,
                     baseo, Bt, H, cnt, perm, out);
}